// Round 1
// baseline (672.686 us; speedup 1.0000x reference)
//
#include <hip/hip_runtime.h>
#include <hip/hip_bf16.h>

#define D_MODEL 1024
#define N_HEADS 16
#define HEAD_DIM 64
#define BATCH 4
#define SEQ 2048
#define M_ROWS (BATCH * SEQ)  // 8192

typedef __attribute__((ext_vector_type(8))) __bf16 bf16x8;
typedef __attribute__((ext_vector_type(8))) short short8;
typedef __attribute__((ext_vector_type(4))) float f32x4;

static __device__ __forceinline__ unsigned short f2bf_rne(float f) {
  unsigned int u = __float_as_uint(f);
  u += 0x7FFFu + ((u >> 16) & 1u);
  return (unsigned short)(u >> 16);
}

// ---------------- fp32 -> bf16 conversion (RNE), 4 elems/thread ----------------
__global__ __launch_bounds__(256) void cvt_f32_to_bf16(const float* __restrict__ in,
                                                       unsigned short* __restrict__ out,
                                                       int n4) {
  int i = blockIdx.x * 256 + threadIdx.x;
  if (i >= n4) return;
  float4 f = reinterpret_cast<const float4*>(in)[i];
  ushort4 o;
  o.x = f2bf_rne(f.x); o.y = f2bf_rne(f.y); o.z = f2bf_rne(f.z); o.w = f2bf_rne(f.w);
  reinterpret_cast<ushort4*>(out)[i] = o;
}

// ---------------- GEMM: C[M,N] = A[M,K] * Bw[N,K]^T  (both K-major bf16) ----------------
// 128x128 block tile, BK=32, 256 threads = 4 waves in 2x2, each wave 64x64 (4x4 MFMAs).
template <bool F32OUT>
__global__ __launch_bounds__(256) void gemm_bt(const unsigned short* __restrict__ A,
                                               const unsigned short* __restrict__ Bw,
                                               void* __restrict__ Cp,
                                               int M, int N, int K) {
  __shared__ __align__(16) unsigned short As[128 * 32];
  __shared__ __align__(16) unsigned short Bs[128 * 32];
  const int t = threadIdx.x;
  const int bn = blockIdx.x, bm = blockIdx.y;
  const int wave = t >> 6, lane = t & 63;
  const int wm = (wave >> 1) * 64, wn = (wave & 1) * 64;
  const int lr = lane & 15, quad = lane >> 4;

  f32x4 acc[4][4] = {};

  for (int k0 = 0; k0 < K; k0 += 32) {
    __syncthreads();
    // stage A tile (128x32) and B tile (128x32): 512 chunks of 8 bf16 each, 2 per thread
    for (int c = t; c < 512; c += 256) {
      int row = c >> 2, col8 = (c & 3) << 3;
      uint4 v = *reinterpret_cast<const uint4*>(A + (size_t)(bm * 128 + row) * K + k0 + col8);
      *reinterpret_cast<uint4*>(&As[row * 32 + col8]) = v;
    }
    for (int c = t; c < 512; c += 256) {
      int row = c >> 2, col8 = (c & 3) << 3;
      uint4 v = *reinterpret_cast<const uint4*>(Bw + (size_t)(bn * 128 + row) * K + k0 + col8);
      *reinterpret_cast<uint4*>(&Bs[row * 32 + col8]) = v;
    }
    __syncthreads();

    bf16x8 af[4], bfr[4];
#pragma unroll
    for (int mt = 0; mt < 4; mt++)
      af[mt] = __builtin_bit_cast(
          bf16x8, *reinterpret_cast<const short8*>(&As[(wm + mt * 16 + lr) * 32 + quad * 8]));
#pragma unroll
    for (int nt = 0; nt < 4; nt++)
      bfr[nt] = __builtin_bit_cast(
          bf16x8, *reinterpret_cast<const short8*>(&Bs[(wn + nt * 16 + lr) * 32 + quad * 8]));
#pragma unroll
    for (int mt = 0; mt < 4; mt++)
#pragma unroll
      for (int nt = 0; nt < 4; nt++)
        acc[mt][nt] = __builtin_amdgcn_mfma_f32_16x16x32_bf16(af[mt], bfr[nt], acc[mt][nt], 0, 0, 0);
  }

  // epilogue: C row = quad*4+r, col = lane&15 (m89/m91-verified layout)
#pragma unroll
  for (int mt = 0; mt < 4; mt++) {
#pragma unroll
    for (int nt = 0; nt < 4; nt++) {
      int col = bn * 128 + wn + nt * 16 + lr;
#pragma unroll
      for (int r = 0; r < 4; r++) {
        int row = bm * 128 + wm + mt * 16 + quad * 4 + r;
        if (F32OUT)
          reinterpret_cast<float*>(Cp)[(size_t)row * N + col] = acc[mt][nt][r];
        else
          reinterpret_cast<unsigned short*>(Cp)[(size_t)row * N + col] = f2bf_rne(acc[mt][nt][r]);
      }
    }
  }
}

// ---------------- causal flash attention ----------------
// grid (S/64, H, B), 256 thr = 4 waves; wave w handles q rows [q0, q0+16), q0 = blk*64 + w*16.
// KV tiles of 32. Q,K,V,O all (B*S, D_MODEL) bf16, head h occupying cols [h*64, h*64+64).
__global__ __launch_bounds__(256) void attn_causal(const unsigned short* __restrict__ Q,
                                                   const unsigned short* __restrict__ Km,
                                                   const unsigned short* __restrict__ V,
                                                   unsigned short* __restrict__ O) {
  __shared__ __align__(16) unsigned short plds[4 * 16 * 32];  // per-wave 16x32 P tile
  const int b = blockIdx.z, h = blockIdx.y;
  const int wave = threadIdx.x >> 6, lane = threadIdx.x & 63;
  const int q0 = blockIdx.x * 64 + wave * 16;
  const int lr = lane & 15, quad = lane >> 4;
  unsigned short* pw = &plds[wave * 512];

  const size_t base = (size_t)b * SEQ * D_MODEL + h * HEAD_DIM;
  const unsigned short* Qb = Q + base;
  const unsigned short* Kb = Km + base;
  const unsigned short* Vb = V + base;

  // Q A-fragments: A[m=lr][k=quad*8+j], two K-halves of Dh=64
  bf16x8 qf[2];
#pragma unroll
  for (int kk = 0; kk < 2; kk++)
    qf[kk] = __builtin_bit_cast(
        bf16x8, *reinterpret_cast<const short8*>(Qb + (size_t)(q0 + lr) * D_MODEL + kk * 32 + quad * 8));

  float m_r[4], l_r[4];
  f32x4 o_acc[4] = {};
#pragma unroll
  for (int r = 0; r < 4; r++) { m_r[r] = -1e30f; l_r[r] = 0.f; }

  const int ntiles = (q0 + 15) / 32 + 1;  // kv0 <= q0 always (q0 % 16 == 0)
  for (int kt = 0; kt < ntiles; kt++) {
    const int kv0 = kt * 32;
    // S = Q*K^T for 32 kv cols: two 16-col halves, Dh=64 = 2 MFMA K-steps each
    f32x4 s[2] = {};
#pragma unroll
    for (int j = 0; j < 2; j++) {
#pragma unroll
      for (int kk = 0; kk < 2; kk++) {
        bf16x8 kf = __builtin_bit_cast(
            bf16x8, *reinterpret_cast<const short8*>(
                        Kb + (size_t)(kv0 + j * 16 + lr) * D_MODEL + kk * 32 + quad * 8));
        s[j] = __builtin_amdgcn_mfma_f32_16x16x32_bf16(qf[kk], kf, s[j], 0, 0, 0);
      }
    }

    asm volatile("s_waitcnt lgkmcnt(0)" ::: "memory");  // prev P reads done before overwrite
#pragma unroll
    for (int r = 0; r < 4; r++) {
      const int qpos = q0 + quad * 4 + r;
      float v0 = s[0][r] * 0.125f;           // 1/sqrt(64)
      float v1 = s[1][r] * 0.125f;
      if (kv0 + lr > qpos) v0 = -1e30f;      // causal mask
      if (kv0 + 16 + lr > qpos) v1 = -1e30f;
      float mx = fmaxf(v0, v1);
#pragma unroll
      for (int off = 1; off < 16; off <<= 1) mx = fmaxf(mx, __shfl_xor(mx, off, 64));
      const float m_new = fmaxf(m_r[r], mx);
      const float alpha = __expf(m_r[r] - m_new);
      const float e0 = __expf(v0 - m_new);
      const float e1 = __expf(v1 - m_new);
      float rs = e0 + e1;
#pragma unroll
      for (int off = 1; off < 16; off <<= 1) rs += __shfl_xor(rs, off, 64);
      l_r[r] = l_r[r] * alpha + rs;
      m_r[r] = m_new;
#pragma unroll
      for (int c = 0; c < 4; c++) o_acc[c][r] *= alpha;
      // write P in C-layout to per-wave LDS
      pw[(quad * 4 + r) * 32 + lr] = f2bf_rne(e0);
      pw[(quad * 4 + r) * 32 + 16 + lr] = f2bf_rne(e1);
    }
    asm volatile("s_waitcnt lgkmcnt(0)" ::: "memory");  // wave-local barrier (lockstep wave)
    // re-read P in A-operand layout: A[m=lr][k=quad*8+j]
    bf16x8 pf = __builtin_bit_cast(
        bf16x8, *reinterpret_cast<const short8*>(&pw[lr * 32 + quad * 8]));

    // O += P * V : B[k=quad*8+jj][n=lr] = V[kv0+quad*8+jj][c*16+lr]
#pragma unroll
    for (int c = 0; c < 4; c++) {
      short8 vv;
#pragma unroll
      for (int jj = 0; jj < 8; jj++)
        vv[jj] = (short)Vb[(size_t)(kv0 + quad * 8 + jj) * D_MODEL + c * 16 + lr];
      o_acc[c] = __builtin_amdgcn_mfma_f32_16x16x32_bf16(
          pf, __builtin_bit_cast(bf16x8, vv), o_acc[c], 0, 0, 0);
    }
  }

  // epilogue: O[q, h*64 + c*16 + lr] = o_acc / l
#pragma unroll
  for (int c = 0; c < 4; c++) {
#pragma unroll
    for (int r = 0; r < 4; r++) {
      const int qpos = q0 + quad * 4 + r;
      O[base + (size_t)qpos * D_MODEL + c * 16 + lr] = f2bf_rne(o_acc[c][r] / l_r[r]);
    }
  }
}

// ---------------- launch ----------------
extern "C" void kernel_launch(void* const* d_in, const int* in_sizes, int n_in,
                              void* d_out, int out_size, void* d_ws, size_t ws_size,
                              hipStream_t stream) {
  const float* x  = (const float*)d_in[0];
  const float* Wq = (const float*)d_in[1];
  const float* Wk = (const float*)d_in[2];
  const float* Wv = (const float*)d_in[3];
  const float* Wo = (const float*)d_in[4];
  float* out = (float*)d_out;

  char* ws = (char*)d_ws;
  const size_t SZ_X = (size_t)M_ROWS * D_MODEL * 2;   // 16 MB
  const size_t SZ_W = (size_t)D_MODEL * D_MODEL * 2;  //  2 MB
  unsigned short* xb  = (unsigned short*)(ws);
  unsigned short* wqb = (unsigned short*)(ws + SZ_X);
  unsigned short* wkb = (unsigned short*)(ws + SZ_X + 1 * SZ_W);
  unsigned short* wvb = (unsigned short*)(ws + SZ_X + 2 * SZ_W);
  unsigned short* wob = (unsigned short*)(ws + SZ_X + 3 * SZ_W);
  unsigned short* Qb  = (unsigned short*)(ws + 1 * SZ_X + 4 * SZ_W);
  unsigned short* Kb  = (unsigned short*)(ws + 2 * SZ_X + 4 * SZ_W);
  unsigned short* Vb  = (unsigned short*)(ws + 3 * SZ_X + 4 * SZ_W);
  unsigned short* Ob  = xb;  // x no longer needed after the 3 projections

  const int nx4 = M_ROWS * D_MODEL / 4;   // 2,097,152
  const int nw4 = D_MODEL * D_MODEL / 4;  //   262,144
  cvt_f32_to_bf16<<<nx4 / 256, 256, 0, stream>>>(x, xb, nx4);
  cvt_f32_to_bf16<<<nw4 / 256, 256, 0, stream>>>(Wq, wqb, nw4);
  cvt_f32_to_bf16<<<nw4 / 256, 256, 0, stream>>>(Wk, wkb, nw4);
  cvt_f32_to_bf16<<<nw4 / 256, 256, 0, stream>>>(Wv, wvb, nw4);
  cvt_f32_to_bf16<<<nw4 / 256, 256, 0, stream>>>(Wo, wob, nw4);

  dim3 gg(D_MODEL / 128, M_ROWS / 128);  // (8, 64)
  gemm_bt<false><<<gg, 256, 0, stream>>>(xb, wqb, Qb, M_ROWS, D_MODEL, D_MODEL);
  gemm_bt<false><<<gg, 256, 0, stream>>>(xb, wkb, Kb, M_ROWS, D_MODEL, D_MODEL);
  gemm_bt<false><<<gg, 256, 0, stream>>>(xb, wvb, Vb, M_ROWS, D_MODEL, D_MODEL);

  attn_causal<<<dim3(SEQ / 64, N_HEADS, BATCH), 256, 0, stream>>>(Qb, Kb, Vb, Ob);

  gemm_bt<true><<<gg, 256, 0, stream>>>(Ob, wob, out, M_ROWS, D_MODEL, D_MODEL);
}